// Round 1
// baseline (2673.581 us; speedup 1.0000x reference)
//
#include <hip/hip_runtime.h>

#define NUM_USERS 100000
#define NUM_ITEMS 50000
#define NN (NUM_USERS + NUM_ITEMS)
#define D 64
#define NNZ_CONST 4000000
#define BATCH 8192
#define NUM_LAYERS 3

__global__ __launch_bounds__(256) void init_kernel(
    const float4* __restrict__ ue, const float4* __restrict__ ie,
    float4* __restrict__ e, float4* __restrict__ acc, int nu4, int total4) {
  int i = blockIdx.x * blockDim.x + threadIdx.x;
  if (i >= total4) return;
  float4 v = (i < nu4) ? ue[i] : ie[i - nu4];
  e[i] = v;
  acc[i] = v;
}

__global__ __launch_bounds__(256) void scatter_kernel(
    const float* __restrict__ vals, const int* __restrict__ rows,
    const int* __restrict__ cols, const float* __restrict__ src,
    float* __restrict__ dst, int nnz) {
  long long gid = (long long)blockIdx.x * blockDim.x + threadIdx.x;
  int e = (int)(gid >> 6);
  if (e >= nnz) return;
  int d = (int)(gid & 63);
  float w = vals[e];
  int c = cols[e];
  int r = rows[e];
  float x = src[((long long)c << 6) + d];
  atomicAdd(dst + (((long long)r << 6) + d), w * x);
}

__global__ __launch_bounds__(256) void acc_kernel(
    float4* __restrict__ acc, const float4* __restrict__ e, int total4) {
  int i = blockIdx.x * blockDim.x + threadIdx.x;
  if (i >= total4) return;
  float4 a = acc[i];
  float4 b = e[i];
  a.x += b.x; a.y += b.y; a.z += b.z; a.w += b.w;
  acc[i] = a;
}

__global__ __launch_bounds__(256) void score_kernel(
    const float* __restrict__ acc, const int* __restrict__ ui,
    const int* __restrict__ pi, const int* __restrict__ ni,
    float* __restrict__ out, int batch, int nu) {
  int wid = (int)(((long long)blockIdx.x * blockDim.x + threadIdx.x) >> 6);
  int lane = threadIdx.x & 63;
  if (wid >= batch) return;
  int u = ui[wid];
  int p = pi[wid];
  int n = ni[wid];
  float uv = acc[((long long)u << 6) + lane];
  float pv = acc[((long long)(nu + p) << 6) + lane];
  float nv = acc[((long long)(nu + n) << 6) + lane];
  float s = uv * (pv - nv);
  #pragma unroll
  for (int off = 32; off; off >>= 1) s += __shfl_down(s, off, 64);
  if (lane == 0) out[wid] = s * (1.0f / 16.0f);
}

extern "C" void kernel_launch(void* const* d_in, const int* in_sizes, int n_in,
                              void* d_out, int out_size, void* d_ws, size_t ws_size,
                              hipStream_t stream) {
  const float* user_emb = (const float*)d_in[0];
  const float* item_emb = (const float*)d_in[1];
  const float* adj_vals = (const float*)d_in[2];
  const int* adj_rows = (const int*)d_in[3];
  const int* adj_cols = (const int*)d_in[4];
  const int* user_idx = (const int*)d_in[5];
  const int* pos_idx = (const int*)d_in[6];
  const int* neg_idx = (const int*)d_in[7];

  const int nnz = in_sizes[2];
  const int batch = in_sizes[5];
  const int nu = in_sizes[0] / D;
  const int ni = in_sizes[1] / D;
  const int n_nodes = nu + ni;
  const long long nd = (long long)n_nodes * D;  // floats per embedding table

  float* acc = (float*)d_ws;
  float* e_a = acc + nd;
  float* e_b = e_a + nd;

  const int total4 = (int)(nd / 4);
  const int nu4 = nu * D / 4;

  // init: e_a = concat(user, item); acc = e_a
  {
    int blocks = (total4 + 255) / 256;
    init_kernel<<<blocks, 256, 0, stream>>>((const float4*)user_emb,
                                            (const float4*)item_emb,
                                            (float4*)e_a, (float4*)acc, nu4, total4);
  }

  const long long scatter_work = (long long)nnz * 64;
  const int scatter_blocks = (int)((scatter_work + 255) / 256);
  const int ew_blocks = (total4 + 255) / 256;
  const size_t tbl_bytes = (size_t)nd * sizeof(float);

  float* src = e_a;
  float* dst = e_b;
  for (int layer = 0; layer < NUM_LAYERS; ++layer) {
    hipMemsetAsync(dst, 0, tbl_bytes, stream);
    scatter_kernel<<<scatter_blocks, 256, 0, stream>>>(adj_vals, adj_rows, adj_cols,
                                                       src, dst, nnz);
    acc_kernel<<<ew_blocks, 256, 0, stream>>>((float4*)acc, (const float4*)dst, total4);
    float* t = src; src = dst; dst = t;
  }

  // score: out[b] = (dot(u,p) - dot(u,n)) / 16
  {
    int waves_per_block = 4;  // 256 threads
    int blocks = (batch + waves_per_block - 1) / waves_per_block;
    score_kernel<<<blocks, 256, 0, stream>>>(acc, user_idx, pos_idx, neg_idx,
                                             (float*)d_out, batch, nu);
  }
}

// Round 2
// 986.191 us; speedup vs baseline: 2.7110x; 2.7110x over previous
//
#include <hip/hip_runtime.h>

#define D 64

// ---------------- init: e = concat(user,item); acc = e ----------------
__global__ __launch_bounds__(256) void init_kernel(
    const float4* __restrict__ ue, const float4* __restrict__ ie,
    float4* __restrict__ e, float4* __restrict__ acc, int nu4, int total4) {
  int i = blockIdx.x * blockDim.x + threadIdx.x;
  if (i >= total4) return;
  float4 v = (i < nu4) ? ue[i] : ie[i - nu4];
  e[i] = v;
  acc[i] = v;
}

// ---------------- CSR build ----------------
__global__ __launch_bounds__(256) void hist_kernel(
    const int* __restrict__ rows, int* __restrict__ counts, int nnz) {
  int e = blockIdx.x * blockDim.x + threadIdx.x;
  if (e < nnz) atomicAdd(&counts[rows[e]], 1);
}

// per-block (2048 elems) sum of counts
__global__ __launch_bounds__(256) void block_sum_kernel(
    const int* __restrict__ counts, int* __restrict__ bsum, int nrows) {
  __shared__ int lds[4];
  int base_i = blockIdx.x * 2048 + threadIdx.x * 8;
  int tsum = 0;
  #pragma unroll
  for (int k = 0; k < 8; ++k) {
    int i = base_i + k;
    if (i < nrows) tsum += counts[i];
  }
  #pragma unroll
  for (int off = 32; off; off >>= 1) tsum += __shfl_down(tsum, off, 64);
  if ((threadIdx.x & 63) == 0) lds[threadIdx.x >> 6] = tsum;
  __syncthreads();
  if (threadIdx.x == 0) bsum[blockIdx.x] = lds[0] + lds[1] + lds[2] + lds[3];
}

// single block: exclusive scan of up to 256 block sums
__global__ __launch_bounds__(256) void scan_bsum_kernel(
    const int* __restrict__ bsum, int* __restrict__ boff, int nb) {
  __shared__ int lds[256];
  int v = (threadIdx.x < nb) ? bsum[threadIdx.x] : 0;
  int orig = v;
  lds[threadIdx.x] = v;
  __syncthreads();
  for (int off = 1; off < 256; off <<= 1) {
    int t = (threadIdx.x >= off) ? lds[threadIdx.x - off] : 0;
    __syncthreads();
    v += t;
    lds[threadIdx.x] = v;
    __syncthreads();
  }
  if (threadIdx.x < nb) boff[threadIdx.x] = v - orig;
}

// per-block exclusive scan of counts (+ block offset) -> row_start
__global__ __launch_bounds__(256) void scan_final_kernel(
    const int* __restrict__ counts, const int* __restrict__ boff,
    int* __restrict__ row_start, int nrows) {
  __shared__ int lds[256];
  int base_i = blockIdx.x * 2048 + threadIdx.x * 8;
  int c[8];
  int tsum = 0;
  #pragma unroll
  for (int k = 0; k < 8; ++k) {
    int i = base_i + k;
    c[k] = (i < nrows) ? counts[i] : 0;
    tsum += c[k];
  }
  int v = tsum;
  lds[threadIdx.x] = v;
  __syncthreads();
  for (int off = 1; off < 256; off <<= 1) {
    int t = (threadIdx.x >= off) ? lds[threadIdx.x - off] : 0;
    __syncthreads();
    v += t;
    lds[threadIdx.x] = v;
    __syncthreads();
  }
  int run = boff[blockIdx.x] + (v - tsum);
  #pragma unroll
  for (int k = 0; k < 8; ++k) {
    int i = base_i + k;
    if (i < nrows) row_start[i] = run;
    if (i == nrows - 1) row_start[nrows] = run + c[k];
    run += c[k];
  }
}

__global__ __launch_bounds__(256) void reorder_kernel(
    const float* __restrict__ vals, const int* __restrict__ rows,
    const int* __restrict__ cols, int* __restrict__ cursor,
    int2* __restrict__ edges, int nnz) {
  int e = blockIdx.x * blockDim.x + threadIdx.x;
  if (e >= nnz) return;
  int r = rows[e];
  int pos = atomicAdd(&cursor[r], 1);
  edges[pos] = make_int2(cols[e], __float_as_int(vals[e]));
}

// ---------------- SpMM: one wave per row, lane = dim; fused acc += ----------------
__global__ __launch_bounds__(256) void spmm_csr_kernel(
    const int* __restrict__ row_start, const int2* __restrict__ edges,
    const float* __restrict__ src, float* __restrict__ dst,
    float* __restrict__ acc, int nrows, int write_dst) {
  int wid = (int)(((long long)blockIdx.x * blockDim.x + threadIdx.x) >> 6);
  int lane = threadIdx.x & 63;
  if (wid >= nrows) return;
  int s = row_start[wid];
  int e = row_start[wid + 1];
  float a = 0.f;
  int j = s;
  for (; j + 4 <= e; j += 4) {
    int2 e0 = edges[j];
    int2 e1 = edges[j + 1];
    int2 e2 = edges[j + 2];
    int2 e3 = edges[j + 3];
    float x0 = src[((long long)e0.x << 6) + lane];
    float x1 = src[((long long)e1.x << 6) + lane];
    float x2 = src[((long long)e2.x << 6) + lane];
    float x3 = src[((long long)e3.x << 6) + lane];
    a += __int_as_float(e0.y) * x0;
    a += __int_as_float(e1.y) * x1;
    a += __int_as_float(e2.y) * x2;
    a += __int_as_float(e3.y) * x3;
  }
  for (; j < e; ++j) {
    int2 ed = edges[j];
    a += __int_as_float(ed.y) * src[((long long)ed.x << 6) + lane];
  }
  long long o = ((long long)wid << 6) + lane;
  if (write_dst) dst[o] = a;
  acc[o] += a;
}

// ---------------- fallback path (atomic scatter) ----------------
__global__ __launch_bounds__(256) void scatter_kernel(
    const float* __restrict__ vals, const int* __restrict__ rows,
    const int* __restrict__ cols, const float* __restrict__ src,
    float* __restrict__ dst, int nnz) {
  long long gid = (long long)blockIdx.x * blockDim.x + threadIdx.x;
  int e = (int)(gid >> 6);
  if (e >= nnz) return;
  int d = (int)(gid & 63);
  float w = vals[e];
  float x = src[((long long)cols[e] << 6) + d];
  atomicAdd(dst + (((long long)rows[e] << 6) + d), w * x);
}

__global__ __launch_bounds__(256) void acc_kernel(
    float4* __restrict__ acc, const float4* __restrict__ e, int total4) {
  int i = blockIdx.x * blockDim.x + threadIdx.x;
  if (i >= total4) return;
  float4 a = acc[i];
  float4 b = e[i];
  a.x += b.x; a.y += b.y; a.z += b.z; a.w += b.w;
  acc[i] = a;
}

// ---------------- BPR score ----------------
__global__ __launch_bounds__(256) void score_kernel(
    const float* __restrict__ acc, const int* __restrict__ ui,
    const int* __restrict__ pi, const int* __restrict__ ni,
    float* __restrict__ out, int batch, int nu) {
  int wid = (int)(((long long)blockIdx.x * blockDim.x + threadIdx.x) >> 6);
  int lane = threadIdx.x & 63;
  if (wid >= batch) return;
  int u = ui[wid];
  int p = pi[wid];
  int n = ni[wid];
  float uv = acc[((long long)u << 6) + lane];
  float pv = acc[((long long)(nu + p) << 6) + lane];
  float nv = acc[((long long)(nu + n) << 6) + lane];
  float s = uv * (pv - nv);
  #pragma unroll
  for (int off = 32; off; off >>= 1) s += __shfl_down(s, off, 64);
  if (lane == 0) out[wid] = s * (1.0f / 16.0f);
}

extern "C" void kernel_launch(void* const* d_in, const int* in_sizes, int n_in,
                              void* d_out, int out_size, void* d_ws, size_t ws_size,
                              hipStream_t stream) {
  const float* user_emb = (const float*)d_in[0];
  const float* item_emb = (const float*)d_in[1];
  const float* adj_vals = (const float*)d_in[2];
  const int* adj_rows = (const int*)d_in[3];
  const int* adj_cols = (const int*)d_in[4];
  const int* user_idx = (const int*)d_in[5];
  const int* pos_idx = (const int*)d_in[6];
  const int* neg_idx = (const int*)d_in[7];

  const int nnz = in_sizes[2];
  const int batch = in_sizes[5];
  const int nu = in_sizes[0] / D;
  const int ni = in_sizes[1] / D;
  const int nrows = nu + ni;
  const long long nd = (long long)nrows * D;
  const size_t nd_bytes = (size_t)nd * sizeof(float);

  char* wp = (char*)d_ws;
  float* acc = (float*)wp;            wp += nd_bytes;
  float* e_a = (float*)wp;            wp += nd_bytes;
  float* e_b = (float*)wp;            wp += nd_bytes;

  const int total4 = (int)(nd / 4);
  const int nu4 = nu * D / 4;
  const int ew_blocks = (total4 + 255) / 256;
  const int edge_blocks = (nnz + 255) / 256;
  const int nb = (nrows + 2047) / 2048;

  // init: e_a = concat(user,item); acc = e_a
  init_kernel<<<ew_blocks, 256, 0, stream>>>(
      (const float4*)user_emb, (const float4*)item_emb,
      (float4*)e_a, (float4*)acc, nu4, total4);

  const size_t csr_bytes = (size_t)nnz * 8 + (size_t)(nrows + 1) * 4 +
                           (size_t)nrows * 4 + 2 * 256 * 4;
  const bool fast = (ws_size >= 3 * nd_bytes + csr_bytes) && (nb <= 256);

  if (fast) {
    int2* edges = (int2*)wp;          wp += (size_t)nnz * 8;
    int* row_start = (int*)wp;        wp += (size_t)(nrows + 1) * 4;
    int* cursor = (int*)wp;           wp += (size_t)nrows * 4;   // also counts
    int* bsum = (int*)wp;             wp += 256 * 4;
    int* boff = (int*)wp;

    // CSR build: counts -> scan -> reorder
    hipMemsetAsync(cursor, 0, (size_t)nrows * 4, stream);
    hist_kernel<<<edge_blocks, 256, 0, stream>>>(adj_rows, cursor, nnz);
    block_sum_kernel<<<nb, 256, 0, stream>>>(cursor, bsum, nrows);
    scan_bsum_kernel<<<1, 256, 0, stream>>>(bsum, boff, nb);
    scan_final_kernel<<<nb, 256, 0, stream>>>(cursor, boff, row_start, nrows);
    hipMemcpyAsync(cursor, row_start, (size_t)nrows * 4,
                   hipMemcpyDeviceToDevice, stream);
    reorder_kernel<<<edge_blocks, 256, 0, stream>>>(adj_vals, adj_rows, adj_cols,
                                                    cursor, edges, nnz);

    const int spmm_blocks = (nrows + 3) / 4;  // 4 waves/block, wave per row
    float* src = e_a;
    float* dst = e_b;
    for (int layer = 0; layer < 3; ++layer) {
      int write_dst = (layer < 2) ? 1 : 0;
      spmm_csr_kernel<<<spmm_blocks, 256, 0, stream>>>(
          row_start, edges, src, dst, acc, nrows, write_dst);
      float* t = src; src = dst; dst = t;
    }
  } else {
    // fallback: atomic scatter path
    const long long scatter_work = (long long)nnz * 64;
    const int scatter_blocks = (int)((scatter_work + 255) / 256);
    float* src = e_a;
    float* dst = e_b;
    for (int layer = 0; layer < 3; ++layer) {
      hipMemsetAsync(dst, 0, nd_bytes, stream);
      scatter_kernel<<<scatter_blocks, 256, 0, stream>>>(adj_vals, adj_rows,
                                                         adj_cols, src, dst, nnz);
      acc_kernel<<<ew_blocks, 256, 0, stream>>>((float4*)acc, (const float4*)dst,
                                                total4);
      float* t = src; src = dst; dst = t;
    }
  }

  // score: out[b] = (dot(u,p) - dot(u,n)) / 16
  score_kernel<<<(batch + 3) / 4, 256, 0, stream>>>(
      acc, user_idx, pos_idx, neg_idx, (float*)d_out, batch, nu);
}

// Round 3
// 637.142 us; speedup vs baseline: 4.1962x; 1.5478x over previous
//
#include <hip/hip_runtime.h>

#define D 64
#define MAXNB 1024
#define CHUNK 4096

// ---------------- init: e = concat(user,item); acc = e ----------------
__global__ __launch_bounds__(256) void init_kernel(
    const float4* __restrict__ ue, const float4* __restrict__ ie,
    float4* __restrict__ e, float4* __restrict__ acc, int nu4, int total4) {
  int i = blockIdx.x * blockDim.x + threadIdx.x;
  if (i >= total4) return;
  float4 v = (i < nu4) ? ue[i] : ie[i - nu4];
  e[i] = v;
  acc[i] = v;
}

// ---------------- bucket histogram (bucket = row>>8) ----------------
__global__ __launch_bounds__(256) void bucket_hist_kernel(
    const int* __restrict__ rows, int* __restrict__ counts, int nnz, int nb) {
  __shared__ int h[MAXNB];
  int t = threadIdx.x;
  for (int i = t; i < nb; i += 256) h[i] = 0;
  __syncthreads();
  for (int e = blockIdx.x * 256 + t; e < nnz; e += gridDim.x * 256)
    atomicAdd(&h[rows[e] >> 8], 1);
  __syncthreads();
  for (int i = t; i < nb; i += 256)
    if (h[i]) atomicAdd(&counts[i], h[i]);
}

// ---------------- single-block scan of bucket counts -> base ----------------
__global__ __launch_bounds__(1024) void bucket_scan_kernel(
    const int* __restrict__ counts, int* __restrict__ base, int nb) {
  __shared__ int lds[1024];
  int t = threadIdx.x;
  int v = (t < nb) ? counts[t] : 0;
  lds[t] = v;
  __syncthreads();
  for (int off = 1; off < 1024; off <<= 1) {
    int add = (t >= off) ? lds[t - off] : 0;
    __syncthreads();
    lds[t] += add;
    __syncthreads();
  }
  if (t < nb) base[t + 1] = lds[t];
  if (t == 0) base[0] = 0;
}

// ---------------- bin: scatter edges into bucket-grouped runs ----------------
// record: x = col | (row&255)<<24 ; y = val bits
__global__ __launch_bounds__(256) void bin_kernel(
    const float* __restrict__ vals, const int* __restrict__ rows,
    const int* __restrict__ cols, int* __restrict__ cursor,
    int2* __restrict__ binned, int nnz, int nb) {
  __shared__ int lh[MAXNB];
  __shared__ int gb[MAXNB];
  int t = threadIdx.x;
  int base_e = blockIdx.x * CHUNK;
  for (int i = t; i < nb; i += 256) lh[i] = 0;
  __syncthreads();
  int myb[16], myr[16];
  #pragma unroll
  for (int k = 0; k < 16; ++k) {
    int e = base_e + k * 256 + t;
    if (e < nnz) {
      int b = rows[e] >> 8;
      myb[k] = b;
      myr[k] = atomicAdd(&lh[b], 1);
    } else {
      myb[k] = -1;
    }
  }
  __syncthreads();
  for (int i = t; i < nb; i += 256) {
    int c = lh[i];
    gb[i] = c ? atomicAdd(&cursor[i], c) : 0;
  }
  __syncthreads();
  #pragma unroll
  for (int k = 0; k < 16; ++k) {
    int e = base_e + k * 256 + t;
    if (e < nnz) {
      int rx = (cols[e] & 0x00FFFFFF) | ((rows[e] & 255) << 24);
      binned[gb[myb[k]] + myr[k]] = make_int2(rx, __float_as_int(vals[e]));
    }
  }
}

// ---------------- place: exact CSR within bucket + row_start ----------------
__global__ __launch_bounds__(256) void place_kernel(
    const int2* __restrict__ binned, const int* __restrict__ base,
    int2* __restrict__ edges, int* __restrict__ row_start, int nrows, int nb) {
  __shared__ int rh[256];
  __shared__ int cur[256];
  int b = blockIdx.x;
  int t = threadIdx.x;
  int start = base[b];
  int cnt = base[b + 1] - start;
  int r0 = b << 8;
  rh[t] = 0;
  __syncthreads();
  for (int i = t; i < cnt; i += 256) {
    unsigned x = (unsigned)binned[start + i].x;
    atomicAdd(&rh[x >> 24], 1);
  }
  __syncthreads();
  int myc = rh[t];
  for (int off = 1; off < 256; off <<= 1) {
    int add = (t >= off) ? rh[t - off] : 0;
    __syncthreads();
    rh[t] += add;
    __syncthreads();
  }
  int excl = rh[t] - myc;  // exclusive scan value
  int r = r0 + t;
  if (r < nrows) row_start[r] = start + excl;
  if (b == nb - 1 && t == 0) row_start[nrows] = base[nb];
  cur[t] = start + excl;
  __syncthreads();
  for (int i = t; i < cnt; i += 256) {
    int2 rec = binned[start + i];
    unsigned x = (unsigned)rec.x;
    int pos = atomicAdd(&cur[x >> 24], 1);
    edges[pos] = make_int2((int)(x & 0x00FFFFFFu), rec.y);
  }
}

// ---------------- SpMM: one wave per row, lane = dim; fused acc += ----------------
__global__ __launch_bounds__(256) void spmm_csr_kernel(
    const int* __restrict__ row_start, const int2* __restrict__ edges,
    const float* __restrict__ src, float* __restrict__ dst,
    float* __restrict__ acc, int nrows, int write_dst) {
  int wid = (int)(((long long)blockIdx.x * blockDim.x + threadIdx.x) >> 6);
  int lane = threadIdx.x & 63;
  if (wid >= nrows) return;
  int s = row_start[wid];
  int e = row_start[wid + 1];
  float a = 0.f;
  int j = s;
  for (; j + 8 <= e; j += 8) {
    int2 E[8];
    float X[8];
    #pragma unroll
    for (int k = 0; k < 8; ++k) E[k] = edges[j + k];
    #pragma unroll
    for (int k = 0; k < 8; ++k) X[k] = src[((long long)E[k].x << 6) + lane];
    #pragma unroll
    for (int k = 0; k < 8; ++k) a += __int_as_float(E[k].y) * X[k];
  }
  for (; j < e; ++j) {
    int2 ed = edges[j];
    a += __int_as_float(ed.y) * src[((long long)ed.x << 6) + lane];
  }
  long long o = ((long long)wid << 6) + lane;
  if (write_dst) dst[o] = a;
  acc[o] += a;
}

// ---------------- fallback path (atomic scatter) ----------------
__global__ __launch_bounds__(256) void scatter_kernel(
    const float* __restrict__ vals, const int* __restrict__ rows,
    const int* __restrict__ cols, const float* __restrict__ src,
    float* __restrict__ dst, int nnz) {
  long long gid = (long long)blockIdx.x * blockDim.x + threadIdx.x;
  int e = (int)(gid >> 6);
  if (e >= nnz) return;
  int d = (int)(gid & 63);
  float w = vals[e];
  float x = src[((long long)cols[e] << 6) + d];
  atomicAdd(dst + (((long long)rows[e] << 6) + d), w * x);
}

__global__ __launch_bounds__(256) void acc_kernel(
    float4* __restrict__ acc, const float4* __restrict__ e, int total4) {
  int i = blockIdx.x * blockDim.x + threadIdx.x;
  if (i >= total4) return;
  float4 a = acc[i];
  float4 b = e[i];
  a.x += b.x; a.y += b.y; a.z += b.z; a.w += b.w;
  acc[i] = a;
}

// ---------------- BPR score ----------------
__global__ __launch_bounds__(256) void score_kernel(
    const float* __restrict__ acc, const int* __restrict__ ui,
    const int* __restrict__ pi, const int* __restrict__ ni,
    float* __restrict__ out, int batch, int nu) {
  int wid = (int)(((long long)blockIdx.x * blockDim.x + threadIdx.x) >> 6);
  int lane = threadIdx.x & 63;
  if (wid >= batch) return;
  int u = ui[wid];
  int p = pi[wid];
  int n = ni[wid];
  float uv = acc[((long long)u << 6) + lane];
  float pv = acc[((long long)(nu + p) << 6) + lane];
  float nv = acc[((long long)(nu + n) << 6) + lane];
  float s = uv * (pv - nv);
  #pragma unroll
  for (int off = 32; off; off >>= 1) s += __shfl_down(s, off, 64);
  if (lane == 0) out[wid] = s * (1.0f / 16.0f);
}

extern "C" void kernel_launch(void* const* d_in, const int* in_sizes, int n_in,
                              void* d_out, int out_size, void* d_ws, size_t ws_size,
                              hipStream_t stream) {
  const float* user_emb = (const float*)d_in[0];
  const float* item_emb = (const float*)d_in[1];
  const float* adj_vals = (const float*)d_in[2];
  const int* adj_rows = (const int*)d_in[3];
  const int* adj_cols = (const int*)d_in[4];
  const int* user_idx = (const int*)d_in[5];
  const int* pos_idx = (const int*)d_in[6];
  const int* neg_idx = (const int*)d_in[7];

  const int nnz = in_sizes[2];
  const int batch = in_sizes[5];
  const int nu = in_sizes[0] / D;
  const int ni = in_sizes[1] / D;
  const int nrows = nu + ni;
  const int nb = (nrows + 255) / 256;
  const long long nd = (long long)nrows * D;
  const size_t nd_bytes = (size_t)nd * sizeof(float);
  const size_t edges_bytes = (size_t)nnz * 8;

  char* wp = (char*)d_ws;
  float* acc = (float*)wp;            wp += nd_bytes;
  float* e_a = (float*)wp;            wp += nd_bytes;
  float* e_b = (float*)wp;            wp += nd_bytes;   // aliased with `binned`
  int2* binned = (int2*)e_b;

  const int total4 = (int)(nd / 4);
  const int nu4 = nu * D / 4;
  const int ew_blocks = (total4 + 255) / 256;

  // init: e_a = concat(user,item); acc = e_a
  init_kernel<<<ew_blocks, 256, 0, stream>>>(
      (const float4*)user_emb, (const float4*)item_emb,
      (float4*)e_a, (float4*)acc, nu4, total4);

  const size_t tail_bytes = edges_bytes + (size_t)(nrows + 1) * 4 +
                            (size_t)(nb + 1) * 4 + 2 * (size_t)nb * 4;
  const bool fast = (ws_size >= 3 * nd_bytes + tail_bytes) && (nb <= MAXNB) &&
                    (edges_bytes <= nd_bytes) && (nnz < 16000000);

  if (fast) {
    int2* edges = (int2*)wp;          wp += edges_bytes;
    int* row_start = (int*)wp;        wp += (size_t)(nrows + 1) * 4;
    int* base = (int*)wp;             wp += (size_t)(nb + 1) * 4;
    int* counts = (int*)wp;           wp += (size_t)nb * 4;
    int* cursor = (int*)wp;

    hipMemsetAsync(counts, 0, (size_t)nb * 4, stream);
    bucket_hist_kernel<<<512, 256, 0, stream>>>(adj_rows, counts, nnz, nb);
    bucket_scan_kernel<<<1, 1024, 0, stream>>>(counts, base, nb);
    hipMemcpyAsync(cursor, base, (size_t)nb * 4, hipMemcpyDeviceToDevice, stream);
    bin_kernel<<<(nnz + CHUNK - 1) / CHUNK, 256, 0, stream>>>(
        adj_vals, adj_rows, adj_cols, cursor, binned, nnz, nb);
    place_kernel<<<nb, 256, 0, stream>>>(binned, base, edges, row_start, nrows, nb);

    const int spmm_blocks = (nrows + 3) / 4;  // 4 waves/block, wave per row
    float* src = e_a;
    float* dst = e_b;
    for (int layer = 0; layer < 3; ++layer) {
      int write_dst = (layer < 2) ? 1 : 0;
      spmm_csr_kernel<<<spmm_blocks, 256, 0, stream>>>(
          row_start, edges, src, dst, acc, nrows, write_dst);
      float* t = src; src = dst; dst = t;
    }
  } else {
    // fallback: atomic scatter path
    const long long scatter_work = (long long)nnz * 64;
    const int scatter_blocks = (int)((scatter_work + 255) / 256);
    float* src = e_a;
    float* dst = e_b;
    for (int layer = 0; layer < 3; ++layer) {
      hipMemsetAsync(dst, 0, nd_bytes, stream);
      scatter_kernel<<<scatter_blocks, 256, 0, stream>>>(adj_vals, adj_rows,
                                                         adj_cols, src, dst, nnz);
      acc_kernel<<<ew_blocks, 256, 0, stream>>>((float4*)acc, (const float4*)dst,
                                                total4);
      float* t = src; src = dst; dst = t;
    }
  }

  // score: out[b] = (dot(u,p) - dot(u,n)) / 16
  score_kernel<<<(batch + 3) / 4, 256, 0, stream>>>(
      acc, user_idx, pos_idx, neg_idx, (float*)d_out, batch, nu);
}

// Round 4
// 393.326 us; speedup vs baseline: 6.7974x; 1.6199x over previous
//
#include <hip/hip_runtime.h>
#include <hip/hip_bf16.h>

#define D 64
#define MAXNB 1024
#define CHUNK 4096

static __device__ __forceinline__ float bf_lo(unsigned v) {
  return __uint_as_float(v << 16);
}
static __device__ __forceinline__ float bf_hi(unsigned v) {
  return __uint_as_float(v & 0xffff0000u);
}
static __device__ __forceinline__ unsigned pack_bf2(float a, float b) {
  __hip_bfloat16 x = __float2bfloat16(a);
  __hip_bfloat16 y = __float2bfloat16(b);
  unsigned short ux = *reinterpret_cast<unsigned short*>(&x);
  unsigned short uy = *reinterpret_cast<unsigned short*>(&y);
  return (unsigned)ux | ((unsigned)uy << 16);
}

// ---------------- convert: e0_bf = bf16(concat(user,item)) ----------------
__global__ __launch_bounds__(256) void convert_kernel(
    const float4* __restrict__ ue, const float4* __restrict__ ie,
    uint2* __restrict__ out, int nu4, int total4) {
  int i = blockIdx.x * blockDim.x + threadIdx.x;
  if (i >= total4) return;
  float4 v = (i < nu4) ? ue[i] : ie[i - nu4];
  out[i] = make_uint2(pack_bf2(v.x, v.y), pack_bf2(v.z, v.w));
}

// ---------------- bucket histogram (bucket = row>>8) ----------------
__global__ __launch_bounds__(256) void bucket_hist_kernel(
    const int* __restrict__ rows, int* __restrict__ counts, int nnz, int nb) {
  __shared__ int h[MAXNB];
  int t = threadIdx.x;
  for (int i = t; i < nb; i += 256) h[i] = 0;
  __syncthreads();
  for (int e = blockIdx.x * 256 + t; e < nnz; e += gridDim.x * 256)
    atomicAdd(&h[rows[e] >> 8], 1);
  __syncthreads();
  for (int i = t; i < nb; i += 256)
    if (h[i]) atomicAdd(&counts[i], h[i]);
}

// ---------------- single-block scan of bucket counts -> base ----------------
__global__ __launch_bounds__(1024) void bucket_scan_kernel(
    const int* __restrict__ counts, int* __restrict__ base, int nb) {
  __shared__ int lds[1024];
  int t = threadIdx.x;
  int v = (t < nb) ? counts[t] : 0;
  lds[t] = v;
  __syncthreads();
  for (int off = 1; off < 1024; off <<= 1) {
    int add = (t >= off) ? lds[t - off] : 0;
    __syncthreads();
    lds[t] += add;
    __syncthreads();
  }
  if (t < nb) base[t + 1] = lds[t];
  if (t == 0) base[0] = 0;
}

// ---------------- bin: scatter edges into bucket-grouped runs ----------------
// record: x = col | (row&255)<<24 ; y = val bits
__global__ __launch_bounds__(256) void bin_kernel(
    const float* __restrict__ vals, const int* __restrict__ rows,
    const int* __restrict__ cols, int* __restrict__ cursor,
    int2* __restrict__ binned, int nnz, int nb) {
  __shared__ int lh[MAXNB];
  __shared__ int gb[MAXNB];
  int t = threadIdx.x;
  int base_e = blockIdx.x * CHUNK;
  for (int i = t; i < nb; i += 256) lh[i] = 0;
  __syncthreads();
  int myb[16], myr[16];
  #pragma unroll
  for (int k = 0; k < 16; ++k) {
    int e = base_e + k * 256 + t;
    if (e < nnz) {
      int b = rows[e] >> 8;
      myb[k] = b;
      myr[k] = atomicAdd(&lh[b], 1);
    } else {
      myb[k] = -1;
    }
  }
  __syncthreads();
  for (int i = t; i < nb; i += 256) {
    int c = lh[i];
    gb[i] = c ? atomicAdd(&cursor[i], c) : 0;
  }
  __syncthreads();
  #pragma unroll
  for (int k = 0; k < 16; ++k) {
    int e = base_e + k * 256 + t;
    if (e < nnz) {
      int rx = (cols[e] & 0x00FFFFFF) | ((rows[e] & 255) << 24);
      binned[gb[myb[k]] + myr[k]] = make_int2(rx, __float_as_int(vals[e]));
    }
  }
}

// ---------------- place: exact CSR within bucket + row_start ----------------
__global__ __launch_bounds__(256) void place_kernel(
    const int2* __restrict__ binned, const int* __restrict__ base,
    int2* __restrict__ edges, int* __restrict__ row_start, int nrows, int nb) {
  __shared__ int rh[256];
  __shared__ int cur[256];
  int b = blockIdx.x;
  int t = threadIdx.x;
  int start = base[b];
  int cnt = base[b + 1] - start;
  int r0 = b << 8;
  rh[t] = 0;
  __syncthreads();
  for (int i = t; i < cnt; i += 256) {
    unsigned x = (unsigned)binned[start + i].x;
    atomicAdd(&rh[x >> 24], 1);
  }
  __syncthreads();
  int myc = rh[t];
  for (int off = 1; off < 256; off <<= 1) {
    int add = (t >= off) ? rh[t - off] : 0;
    __syncthreads();
    rh[t] += add;
    __syncthreads();
  }
  int excl = rh[t] - myc;
  int r = r0 + t;
  if (r < nrows) row_start[r] = start + excl;
  if (b == nb - 1 && t == 0) row_start[nrows] = base[nb];
  cur[t] = start + excl;
  __syncthreads();
  for (int i = t; i < cnt; i += 256) {
    int2 rec = binned[start + i];
    unsigned x = (unsigned)rec.x;
    int pos = atomicAdd(&cur[x >> 24], 1);
    edges[pos] = make_int2((int)(x & 0x00FFFFFFu), rec.y);
  }
}

// ---------------- flags for last-layer row pruning ----------------
__global__ __launch_bounds__(256) void flag_kernel(
    const int* __restrict__ ui, const int* __restrict__ pi,
    const int* __restrict__ ni, unsigned char* __restrict__ flags,
    int batch, int nu) {
  int i = blockIdx.x * blockDim.x + threadIdx.x;
  if (i >= batch) return;
  flags[ui[i]] = 1;
  flags[nu + pi[i]] = 1;
  flags[nu + ni[i]] = 1;
}

// ---------------- SpMM bf16: wave per row; lanes = (edge-pair, dim-pair) ----------------
__global__ __launch_bounds__(256) void spmm_bf16_kernel(
    const int* __restrict__ row_start, const int2* __restrict__ edges,
    const unsigned* __restrict__ src,  // bf16x2 words, 32 words/row
    unsigned* __restrict__ dst,
    const unsigned char* __restrict__ flags, int nrows) {
  int wid = (int)(((long long)blockIdx.x * blockDim.x + threadIdx.x) >> 6);
  if (wid >= nrows) return;
  if (flags && !flags[wid]) return;
  int lane = threadIdx.x & 63;
  int sub = lane >> 5;   // which edge of the pair
  int d2 = lane & 31;    // dim-pair index
  int s = row_start[wid];
  int e = row_start[wid + 1];
  float a0 = 0.f, a1 = 0.f;
  int j = s;
  for (; j + 8 <= e; j += 8) {
    int2 E[4];
    unsigned V[4];
    #pragma unroll
    for (int k = 0; k < 4; ++k) E[k] = edges[j + 2 * k + sub];
    #pragma unroll
    for (int k = 0; k < 4; ++k) V[k] = src[((long long)E[k].x << 5) + d2];
    #pragma unroll
    for (int k = 0; k < 4; ++k) {
      float w = __int_as_float(E[k].y);
      a0 = fmaf(w, bf_lo(V[k]), a0);
      a1 = fmaf(w, bf_hi(V[k]), a1);
    }
  }
  for (; j + 2 <= e; j += 2) {
    int2 ed = edges[j + sub];
    unsigned v = src[((long long)ed.x << 5) + d2];
    float w = __int_as_float(ed.y);
    a0 = fmaf(w, bf_lo(v), a0);
    a1 = fmaf(w, bf_hi(v), a1);
  }
  if (j < e && sub == 0) {
    int2 ed = edges[j];
    unsigned v = src[((long long)ed.x << 5) + d2];
    float w = __int_as_float(ed.y);
    a0 = fmaf(w, bf_lo(v), a0);
    a1 = fmaf(w, bf_hi(v), a1);
  }
  a0 += __shfl_down(a0, 32, 64);
  a1 += __shfl_down(a1, 32, 64);
  if (lane < 32) dst[((long long)wid << 5) + d2] = pack_bf2(a0, a1);
}

// ---------------- score: 2 batch elems per wave; e0 from f32 inputs ----------------
__global__ __launch_bounds__(256) void score2_kernel(
    const float* __restrict__ ue, const float* __restrict__ ie,
    const unsigned* __restrict__ e1, const unsigned* __restrict__ e2,
    const unsigned* __restrict__ e3, const int* __restrict__ ui,
    const int* __restrict__ pi, const int* __restrict__ ni,
    float* __restrict__ out, int batch, int nu) {
  int w = (int)(((long long)blockIdx.x * blockDim.x + threadIdx.x) >> 6);
  int lane = threadIdx.x & 63;
  int half = lane >> 5;
  int d2 = lane & 31;
  int b = w * 2 + half;
  if (b >= batch) return;
  long long un = (long long)ui[b];
  int p = pi[b], n = ni[b];
  long long pn = (long long)(nu + p);
  long long nn_ = (long long)(nu + n);
  float2 U = *(const float2*)(ue + (un << 6) + (d2 << 1));
  float2 P = *(const float2*)(ie + ((long long)p << 6) + (d2 << 1));
  float2 Nv = *(const float2*)(ie + ((long long)n << 6) + (d2 << 1));
  unsigned v;
  v = e1[(un << 5) + d2]; U.x += bf_lo(v); U.y += bf_hi(v);
  v = e2[(un << 5) + d2]; U.x += bf_lo(v); U.y += bf_hi(v);
  v = e3[(un << 5) + d2]; U.x += bf_lo(v); U.y += bf_hi(v);
  v = e1[(pn << 5) + d2]; P.x += bf_lo(v); P.y += bf_hi(v);
  v = e2[(pn << 5) + d2]; P.x += bf_lo(v); P.y += bf_hi(v);
  v = e3[(pn << 5) + d2]; P.x += bf_lo(v); P.y += bf_hi(v);
  v = e1[(nn_ << 5) + d2]; Nv.x += bf_lo(v); Nv.y += bf_hi(v);
  v = e2[(nn_ << 5) + d2]; Nv.x += bf_lo(v); Nv.y += bf_hi(v);
  v = e3[(nn_ << 5) + d2]; Nv.x += bf_lo(v); Nv.y += bf_hi(v);
  float s = U.x * (P.x - Nv.x) + U.y * (P.y - Nv.y);
  #pragma unroll
  for (int off = 16; off; off >>= 1) s += __shfl_down(s, off, 32);
  if (d2 == 0) out[b] = s * (1.0f / 16.0f);
}

// ---------------- fallback path (f32 atomic scatter) ----------------
__global__ __launch_bounds__(256) void init_kernel(
    const float4* __restrict__ ue, const float4* __restrict__ ie,
    float4* __restrict__ e, float4* __restrict__ acc, int nu4, int total4) {
  int i = blockIdx.x * blockDim.x + threadIdx.x;
  if (i >= total4) return;
  float4 v = (i < nu4) ? ue[i] : ie[i - nu4];
  e[i] = v;
  acc[i] = v;
}

__global__ __launch_bounds__(256) void scatter_kernel(
    const float* __restrict__ vals, const int* __restrict__ rows,
    const int* __restrict__ cols, const float* __restrict__ src,
    float* __restrict__ dst, int nnz) {
  long long gid = (long long)blockIdx.x * blockDim.x + threadIdx.x;
  int e = (int)(gid >> 6);
  if (e >= nnz) return;
  int d = (int)(gid & 63);
  float w = vals[e];
  float x = src[((long long)cols[e] << 6) + d];
  atomicAdd(dst + (((long long)rows[e] << 6) + d), w * x);
}

__global__ __launch_bounds__(256) void acc_kernel(
    float4* __restrict__ acc, const float4* __restrict__ e, int total4) {
  int i = blockIdx.x * blockDim.x + threadIdx.x;
  if (i >= total4) return;
  float4 a = acc[i];
  float4 b = e[i];
  a.x += b.x; a.y += b.y; a.z += b.z; a.w += b.w;
  acc[i] = a;
}

__global__ __launch_bounds__(256) void score_kernel(
    const float* __restrict__ acc, const int* __restrict__ ui,
    const int* __restrict__ pi, const int* __restrict__ ni,
    float* __restrict__ out, int batch, int nu) {
  int wid = (int)(((long long)blockIdx.x * blockDim.x + threadIdx.x) >> 6);
  int lane = threadIdx.x & 63;
  if (wid >= batch) return;
  int u = ui[wid];
  int p = pi[wid];
  int n = ni[wid];
  float uv = acc[((long long)u << 6) + lane];
  float pv = acc[((long long)(nu + p) << 6) + lane];
  float nv = acc[((long long)(nu + n) << 6) + lane];
  float s = uv * (pv - nv);
  #pragma unroll
  for (int off = 32; off; off >>= 1) s += __shfl_down(s, off, 64);
  if (lane == 0) out[wid] = s * (1.0f / 16.0f);
}

static inline size_t align_up(size_t x) { return (x + 255) & ~(size_t)255; }

extern "C" void kernel_launch(void* const* d_in, const int* in_sizes, int n_in,
                              void* d_out, int out_size, void* d_ws, size_t ws_size,
                              hipStream_t stream) {
  const float* user_emb = (const float*)d_in[0];
  const float* item_emb = (const float*)d_in[1];
  const float* adj_vals = (const float*)d_in[2];
  const int* adj_rows = (const int*)d_in[3];
  const int* adj_cols = (const int*)d_in[4];
  const int* user_idx = (const int*)d_in[5];
  const int* pos_idx = (const int*)d_in[6];
  const int* neg_idx = (const int*)d_in[7];

  const int nnz = in_sizes[2];
  const int batch = in_sizes[5];
  const int nu = in_sizes[0] / D;
  const int ni = in_sizes[1] / D;
  const int nrows = nu + ni;
  const int nb = (nrows + 255) / 256;
  const long long nd = (long long)nrows * D;
  const size_t nd_bytes = (size_t)nd * sizeof(float);
  const size_t bf_tbl = align_up((size_t)nrows * D * 2);  // bf16 table
  const size_t edges_bytes = align_up((size_t)nnz * 8);

  const int total4 = (int)(nd / 4);
  const int nu4 = nu * D / 4;
  const int ew_blocks = (total4 + 255) / 256;

  const size_t need = 4 * bf_tbl + 2 * edges_bytes +
                      align_up((size_t)(nrows + 1) * 4) +
                      align_up((size_t)(nb + 1) * 4) +
                      2 * align_up((size_t)nb * 4) +
                      align_up((size_t)nrows);
  const bool fast = (ws_size >= need) && (nb <= MAXNB) && (nrows < (1 << 24));

  if (fast) {
    char* wp = (char*)d_ws;
    unsigned* e0b = (unsigned*)wp;    wp += bf_tbl;
    unsigned* e1 = (unsigned*)wp;     wp += bf_tbl;
    unsigned* e2 = (unsigned*)wp;     wp += bf_tbl;
    unsigned* e3 = (unsigned*)wp;     wp += bf_tbl;
    int2* edges = (int2*)wp;          wp += edges_bytes;
    int2* binned = (int2*)wp;         wp += edges_bytes;
    int* row_start = (int*)wp;        wp += align_up((size_t)(nrows + 1) * 4);
    int* base = (int*)wp;             wp += align_up((size_t)(nb + 1) * 4);
    int* counts = (int*)wp;           wp += align_up((size_t)nb * 4);
    int* cursor = (int*)wp;           wp += align_up((size_t)nb * 4);
    unsigned char* flags = (unsigned char*)wp;

    // e0 bf16 conversion
    convert_kernel<<<ew_blocks, 256, 0, stream>>>(
        (const float4*)user_emb, (const float4*)item_emb,
        (uint2*)e0b, nu4, total4);

    // CSR build
    hipMemsetAsync(counts, 0, (size_t)nb * 4, stream);
    bucket_hist_kernel<<<512, 256, 0, stream>>>(adj_rows, counts, nnz, nb);
    bucket_scan_kernel<<<1, 1024, 0, stream>>>(counts, base, nb);
    hipMemcpyAsync(cursor, base, (size_t)nb * 4, hipMemcpyDeviceToDevice, stream);
    bin_kernel<<<(nnz + CHUNK - 1) / CHUNK, 256, 0, stream>>>(
        adj_vals, adj_rows, adj_cols, cursor, binned, nnz, nb);
    place_kernel<<<nb, 256, 0, stream>>>(binned, base, edges, row_start, nrows, nb);

    // flags for last layer
    hipMemsetAsync(flags, 0, (size_t)nrows, stream);
    flag_kernel<<<(batch + 255) / 256, 256, 0, stream>>>(
        user_idx, pos_idx, neg_idx, flags, batch, nu);

    const int spmm_blocks = (nrows + 3) / 4;  // 4 waves/block
    spmm_bf16_kernel<<<spmm_blocks, 256, 0, stream>>>(
        row_start, edges, e0b, e1, (const unsigned char*)nullptr, nrows);
    spmm_bf16_kernel<<<spmm_blocks, 256, 0, stream>>>(
        row_start, edges, e1, e2, (const unsigned char*)nullptr, nrows);
    spmm_bf16_kernel<<<spmm_blocks, 256, 0, stream>>>(
        row_start, edges, e2, e3, flags, nrows);

    score2_kernel<<<(batch / 2 + 3) / 4, 256, 0, stream>>>(
        user_emb, item_emb, e1, e2, e3, user_idx, pos_idx, neg_idx,
        (float*)d_out, batch, nu);
  } else {
    // fallback: f32 atomic scatter path (needs 3 * nd_bytes)
    char* wp = (char*)d_ws;
    float* acc = (float*)wp;          wp += nd_bytes;
    float* e_a = (float*)wp;          wp += nd_bytes;
    float* e_b = (float*)wp;

    init_kernel<<<ew_blocks, 256, 0, stream>>>(
        (const float4*)user_emb, (const float4*)item_emb,
        (float4*)e_a, (float4*)acc, nu4, total4);
    const long long scatter_work = (long long)nnz * 64;
    const int scatter_blocks = (int)((scatter_work + 255) / 256);
    float* src = e_a;
    float* dst = e_b;
    for (int layer = 0; layer < 3; ++layer) {
      hipMemsetAsync(dst, 0, nd_bytes, stream);
      scatter_kernel<<<scatter_blocks, 256, 0, stream>>>(adj_vals, adj_rows,
                                                         adj_cols, src, dst, nnz);
      acc_kernel<<<ew_blocks, 256, 0, stream>>>((float4*)acc, (const float4*)dst,
                                                total4);
      float* t = src; src = dst; dst = t;
    }
    score_kernel<<<(batch + 3) / 4, 256, 0, stream>>>(
        acc, user_idx, pos_idx, neg_idx, (float*)d_out, batch, nu);
  }
}